// Round 7
// baseline (235.292 us; speedup 1.0000x reference)
//
#include <hip/hip_runtime.h>
#include <hip/hip_fp16.h>

static constexpr int HH = 2048;
static constexpr int WW = 2048;
static constexpr int PADT = 24;   // top/bottom pad rows
static constexpr int PADL = 8;    // left/right pad cols
static constexpr int SW   = WW + 2 * PADL;          // 2064
static constexpr int PROWS = HH + 2 * PADT;         // 2096
static constexpr size_t PadElems = (size_t)PROWS * SW;
static constexpr int ROWS = 16;   // output rows per thread in filter kernels

// segment tables for +10 deg: lval(d)=round(d*tan(10deg)), runs of constant offset
__device__ constexpr int CS[9] = {-24,-19,-14,-8,-2, 3, 9,15,20};
__device__ constexpr int CE[9] = {-20,-15, -9,-3, 2, 8,14,19,24};
__device__ constexpr int CO[9] = { -4, -3, -2,-1, 0, 1, 2, 3, 4};

// ---- one slanted segment: vertical run [SS,EE] at col offset OO ----
template<int SS, int EE, int OO>
__device__ __forceinline__ void seg_one(const __half* __restrict__ tp, int h0, int w,
                                        float* __restrict__ acc) {
  constexpr int L = EE - SS + 1;        // 5 or 6
  const __half* p = tp + (h0 + SS + PADT) * SW + (w + OO + PADL);
  float ring[L - 1];
  float s = 0.0f;
#pragma unroll
  for (int k = 0; k < L - 1; ++k) { float v = __half2float(p[k * SW]); ring[k] = v; s += v; }
#pragma unroll
  for (int r = 0; r < ROWS; ++r) {
    float v = __half2float(p[(L - 1 + r) * SW]);
    acc[r] += s + v;
    s += v - ring[r % (L - 1)];
    ring[r % (L - 1)] = v;
  }
}

template<int SGN>   // +1 => +10deg, -1 => -10deg
__device__ __forceinline__ void filt_slant(const __half* __restrict__ tp, int h0, int w,
                                           float* __restrict__ acc) {
  seg_one<-24, -20, -4 * SGN>(tp, h0, w, acc);
  seg_one<-19, -15, -3 * SGN>(tp, h0, w, acc);
  seg_one<-14,  -9, -2 * SGN>(tp, h0, w, acc);
  seg_one< -8,  -3, -1 * SGN>(tp, h0, w, acc);
  seg_one< -2,   2,  0      >(tp, h0, w, acc);
  seg_one<  3,   8,  1 * SGN>(tp, h0, w, acc);
  seg_one<  9,  14,  2 * SGN>(tp, h0, w, acc);
  seg_one< 15,  19,  3 * SGN>(tp, h0, w, acc);
  seg_one< 20,  24,  4 * SGN>(tp, h0, w, acc);
}

// A: 0 => -10deg, 1 => 0deg, 2 => +10deg
template<int A>
__device__ __forceinline__ void filtN(const __half* __restrict__ tp, int h0, int w,
                                      float* __restrict__ acc) {
#pragma unroll
  for (int r = 0; r < ROWS; ++r) acc[r] = 0.0f;
  if constexpr (A == 1) {
    const __half* p = tp + (h0 - 24 + PADT) * SW + (w + PADL);
    float s = 0.0f;
#pragma unroll
    for (int k = 0; k < 48; ++k) s += __half2float(p[k * SW]);
#pragma unroll
    for (int r = 0; r < ROWS; ++r) {
      float vin = __half2float(p[(48 + r) * SW]);
      acc[r] = s + vin;
      s += vin - __half2float(p[r * SW]);
    }
  } else if constexpr (A == 0) {
    filt_slant<-1>(tp, h0, w, acc);
  } else {
    filt_slant<+1>(tp, h0, w, acc);
  }
}

// analytic 1/N (N = in-bounds tap count of zero-padded conv)
template<int A>
__device__ __forceinline__ float rcpcnt(int h, int w) {
  if (h >= 24 && h <= 2023 && w >= 4 && w <= 2043) return 1.0f / 49.0f;
  int cnt = 0;
  if constexpr (A == 1) {
    cnt = min(h + 24, HH - 1) - max(h - 24, 0) + 1;
  } else {
    const int sgn = (A == 0) ? -1 : 1;
#pragma unroll
    for (int j = 0; j < 9; ++j) {
      const int ww = w + sgn * CO[j];
      const int ov = min(h + CE[j], HH - 1) - max(h + CS[j], 0) + 1;
      if (ww >= 0 && ww < WW && ov > 0) cnt += ov;
    }
  }
  return 1.0f / (float)cnt;
}

// ---- pass A: bp = filt(tcur)/N ----
template<int A>
__global__ __launch_bounds__(256) void passA(const __half* __restrict__ tcur,
                                             __half* __restrict__ bp) {
  const int w  = blockIdx.x * 256 + threadIdx.x;
  const int h0 = blockIdx.y * ROWS;
  float acc[ROWS];
  filtN<A>(tcur, h0, w, acc);
#pragma unroll
  for (int r = 0; r < ROWS; ++r) {
    const int h = h0 + r;
    bp[(h + PADT) * SW + (w + PADL)] = __float2half(acc[r] * rcpcnt<A>(h, w));
  }
}

// ---- pass B (mid): tcur[i] -= filt(bp)/N  (in-place; own-pixel read/write only) ----
template<int A>
__global__ __launch_bounds__(256) void passB(const __half* __restrict__ bp,
                                             __half* __restrict__ tcur) {
  const int w  = blockIdx.x * 256 + threadIdx.x;
  const int h0 = blockIdx.y * ROWS;
  float acc[ROWS];
  filtN<A>(bp, h0, w, acc);
#pragma unroll
  for (int r = 0; r < ROWS; ++r) {
    const int h = h0 + r;
    const size_t ip = (size_t)(h + PADT) * SW + (w + PADL);
    tcur[ip] = __float2half(__half2float(tcur[ip]) - acc[r] * rcpcnt<A>(h, w));
  }
}

// ---- pass B (final): res = t0 - (tcur - filt(bp)/N); tcur <- res (fp16, in place);
// global |res| max via wave-reduce + atomicMax (float-as-uint, nonneg => monotone) ----
template<int A>
__global__ __launch_bounds__(256) void passBF(const __half* __restrict__ bp,
                                              __half* __restrict__ tcur,
                                              const __half* __restrict__ t0h,
                                              unsigned int* __restrict__ scaleU) {
  const int w  = blockIdx.x * 256 + threadIdx.x;
  const int h0 = blockIdx.y * ROWS;
  float acc[ROWS];
  filtN<A>(bp, h0, w, acc);
  float m = 0.0f;
#pragma unroll
  for (int r = 0; r < ROWS; ++r) {
    const int h = h0 + r;
    const size_t i  = (size_t)h * WW + w;
    const size_t ip = (size_t)(h + PADT) * SW + (w + PADL);
    const float res = __half2float(t0h[i]) - __half2float(tcur[ip]) +
                      acc[r] * rcpcnt<A>(h, w);
    tcur[ip] = __float2half(res);
    m = fmaxf(m, fabsf(res));
  }
#pragma unroll
  for (int off = 32; off >= 1; off >>= 1) m = fmaxf(m, __shfl_xor(m, off));
  if ((threadIdx.x & 63) == 0) atomicMax(scaleU, __float_as_uint(m));
}

__global__ void zeroscale(unsigned int* __restrict__ scaleU) { *scaleU = 0u; }

// ---- quantize tcur (holds D, fp16) into quad-dup int8:
// P4[s*WW+x] bytes = (D[2s][x], D[2s][x+1], D[2s+1][x], D[2s+1][x+1]) ----
__global__ __launch_bounds__(256) void quantquad(const __half* __restrict__ tcur,
                                                 const unsigned int* __restrict__ scaleU,
                                                 unsigned int* __restrict__ P4) {
  const int i = blockIdx.x * 256 + threadIdx.x;   // over (HH/2)*WW
  const int s = i >> 11, x = i & (WW - 1);
  const float m = __uint_as_float(*scaleU);
  const float inv = (m > 0.0f) ? 127.0f / m : 0.0f;
  const int ha = 2 * s, hb = ha + 1;
  const size_t pa = (size_t)(ha + PADT) * SW + (x + PADL);
  const size_t pb = (size_t)(hb + PADT) * SW + (x + PADL);
  const float a0 = __half2float(tcur[pa]);
  const float b0 = __half2float(tcur[pb]);
  const float a1 = (x < WW - 1) ? __half2float(tcur[pa + 1]) : a0;
  const float b1 = (x < WW - 1) ? __half2float(tcur[pb + 1]) : b0;
  int qa0 = min(max((int)rintf(a0 * inv), -127), 127);
  int qa1 = min(max((int)rintf(a1 * inv), -127), 127);
  int qb0 = min(max((int)rintf(b0 * inv), -127), 127);
  int qb1 = min(max((int)rintf(b1 * inv), -127), 127);
  P4[i] = (unsigned int)(qa0 & 0xff) | ((unsigned int)(qa1 & 0xff) << 8) |
          ((unsigned int)(qb0 & 0xff) << 16) | ((unsigned int)(qb1 & 0xff) << 24);
}

// zero the pad frame of both fp16 staging buffers
__global__ __launch_bounds__(64) void zeropad(__half* __restrict__ tp, __half* __restrict__ bp) {
  __half* buf = blockIdx.y ? bp : tp;
  const int row = blockIdx.x;
  __half* r = buf + (size_t)row * SW;
  const __half z = __float2half(0.0f);
  if (row < PADT || row >= PADT + HH) {
    for (int c = threadIdx.x; c < SW; c += 64) r[c] = z;
  } else if (threadIdx.x < PADL) {
    r[threadIdx.x] = z;
    r[PADL + WW + threadIdx.x] = z;
  }
}

// tcur interior = t0h = y - X
__global__ __launch_bounds__(256) void sub2pad(const float* __restrict__ y,
                                               const float* __restrict__ X,
                                               __half* __restrict__ tcur,
                                               __half* __restrict__ t0h) {
  const int i = blockIdx.x * 256 + threadIdx.x;
  const int h = i >> 11, w = i & (WW - 1);
  const __half d = __float2half(y[i] - X[i]);
  tcur[(h + PADT) * SW + (w + PADL)] = d;
  t0h[i] = d;
}

__device__ __forceinline__ float reflectf(float x, int size) {
  const float span = (float)(size - 1);
  const float ax = fabsf(x);
  const float extra = fmodf(ax, span);
  const float flips = floorf(ax / span);
  float r = (fmodf(flips, 2.0f) == 0.0f) ? extra : (span - extra);
  return fminf(fmaxf(r, 0.0f), span);
}

__global__ __launch_bounds__(256) void gather_k(const unsigned int* __restrict__ P4,
                                                const unsigned int* __restrict__ scaleU,
                                                const unsigned long long* __restrict__ coorU,
                                                const float* __restrict__ hX,
                                                float* __restrict__ out) {
  const int i = blockIdx.x * 256 + threadIdx.x;
  const unsigned long long cu = __builtin_nontemporal_load(&coorU[i]);
  union { unsigned long long u; float f[2]; } cc; cc.u = cu;
  const float gx = reflectf((cc.f[0] + 1.0f) * 0.5f * (float)(WW - 1), WW);
  const float gy = reflectf((cc.f[1] + 1.0f) * 0.5f * (float)(HH - 1), HH);
  const float x0 = floorf(gx), y0 = floorf(gy);
  const float wx = gx - x0, wy = gy - y0;
  const int xi0 = min(max((int)x0, 0), WW - 1);
  const int yi0 = min(max((int)y0, 0), HH - 1);
  const int yi1 = min(max((int)(y0 + 1.0f), 0), HH - 1);
  const int s0 = yi0 >> 1, s1 = yi1 >> 1;
  const unsigned int u0 = P4[s0 * WW + xi0];   // rows (2s0,2s0+1) x cols (xi0,xi0+1)
  const unsigned int u1 = P4[s1 * WW + xi0];
  const int sh0 = (yi0 & 1) << 4;              // 0 or 16
  const int sh1 = (yi1 & 1) << 4;
  const float v00 = (float)(signed char)(u0 >> sh0);
  const float v01 = (float)(signed char)(u0 >> (sh0 + 8));
  const float v10 = (float)(signed char)(u1 >> sh1);
  const float v11 = (float)(signed char)(u1 >> (sh1 + 8));
  const float sc = __uint_as_float(*scaleU) * (1.0f / 127.0f);  // wave-uniform
  const float hx = __builtin_nontemporal_load(&hX[i]);
  const float bil = v00 * (1.0f - wx) * (1.0f - wy) + v01 * wx * (1.0f - wy) +
                    v10 * (1.0f - wx) * wy + v11 * wx * wy;
  __builtin_nontemporal_store(bil * sc + hx, &out[i]);
}

extern "C" void kernel_launch(void* const* d_in, const int* in_sizes, int n_in,
                              void* d_out, int out_size, void* d_ws, size_t ws_size,
                              hipStream_t stream) {
  const float* X    = (const float*)d_in[0];
  const float* y    = (const float*)d_in[1];
  const float* hX   = (const float*)d_in[2];
  const float* coor = (const float*)d_in[3];
  float* out = (float*)d_out;

  __half* tcur = (__half*)d_ws;                      // padded t, fp16,  8.65 MB
  __half* bp   = tcur + PadElems;                    // padded b, fp16,  8.65 MB
  __half* t0h  = bp + PadElems;                      // t0 = y-X, fp16,  8.39 MB
  unsigned int* P4 = (unsigned int*)(t0h + (size_t)HH * WW);  // quad-dup int8 D, 8.39 MB
  unsigned int* scaleU = P4 + (size_t)(HH / 2) * WW; // 4 B

  const int n = HH * WW;
  dim3 fgrd(WW / 256, HH / ROWS, 1);

  zeroscale<<<1, 1, 0, stream>>>(scaleU);
  zeropad<<<dim3(PROWS, 2, 1), 64, 0, stream>>>(tcur, bp);
  sub2pad<<<n / 256, 256, 0, stream>>>(y, X, tcur, t0h);

  // iteration 0: -10deg
  passA<0><<<fgrd, 256, 0, stream>>>(tcur, bp);
  passB<0><<<fgrd, 256, 0, stream>>>(bp, tcur);
  // iteration 1: 0deg
  passA<1><<<fgrd, 256, 0, stream>>>(tcur, bp);
  passB<1><<<fgrd, 256, 0, stream>>>(bp, tcur);
  // iteration 2: +10deg  (tcur <- D = t0 - t3; global max into scaleU)
  passA<2><<<fgrd, 256, 0, stream>>>(tcur, bp);
  passBF<2><<<fgrd, 256, 0, stream>>>(bp, tcur, t0h, scaleU);

  quantquad<<<(n / 2) / 256, 256, 0, stream>>>(tcur, scaleU, P4);
  gather_k<<<n / 256, 256, 0, stream>>>(P4, scaleU, (const unsigned long long*)coor, hX, out);
}

// Round 8
// 217.053 us; speedup vs baseline: 1.0840x; 1.0840x over previous
//
#include <hip/hip_runtime.h>
#include <hip/hip_fp16.h>

static constexpr int HH = 2048;
static constexpr int WW = 2048;
static constexpr int PADT = 24;   // top/bottom pad rows
static constexpr int PADL = 8;    // left/right pad cols
static constexpr int SW   = WW + 2 * PADL;          // 2064
static constexpr int PROWS = HH + 2 * PADT;         // 2096
static constexpr size_t PadElems = (size_t)PROWS * SW;
static constexpr int ROWS = 16;   // output rows per thread in filter kernels

// segment tables for +10 deg: lval(d)=round(d*tan(10deg)), runs of constant offset
__device__ constexpr int CS[9] = {-24,-19,-14,-8,-2, 3, 9,15,20};
__device__ constexpr int CE[9] = {-20,-15, -9,-3, 2, 8,14,19,24};
__device__ constexpr int CO[9] = { -4, -3, -2,-1, 0, 1, 2, 3, 4};

// ---- one slanted segment: vertical run [SS,EE] at col offset OO ----
template<int SS, int EE, int OO>
__device__ __forceinline__ void seg_one(const __half* __restrict__ tp, int h0, int w,
                                        float* __restrict__ acc) {
  constexpr int L = EE - SS + 1;        // 5 or 6
  const __half* p = tp + (h0 + SS + PADT) * SW + (w + OO + PADL);
  float ring[L - 1];
  float s = 0.0f;
#pragma unroll
  for (int k = 0; k < L - 1; ++k) { float v = __half2float(p[k * SW]); ring[k] = v; s += v; }
#pragma unroll
  for (int r = 0; r < ROWS; ++r) {
    float v = __half2float(p[(L - 1 + r) * SW]);
    acc[r] += s + v;
    s += v - ring[r % (L - 1)];
    ring[r % (L - 1)] = v;
  }
}

template<int SGN>   // +1 => +10deg, -1 => -10deg
__device__ __forceinline__ void filt_slant(const __half* __restrict__ tp, int h0, int w,
                                           float* __restrict__ acc) {
#pragma unroll
  for (int r = 0; r < ROWS; ++r) acc[r] = 0.0f;
  seg_one<-24, -20, -4 * SGN>(tp, h0, w, acc);
  seg_one<-19, -15, -3 * SGN>(tp, h0, w, acc);
  seg_one<-14,  -9, -2 * SGN>(tp, h0, w, acc);
  seg_one< -8,  -3, -1 * SGN>(tp, h0, w, acc);
  seg_one< -2,   2,  0      >(tp, h0, w, acc);
  seg_one<  3,   8,  1 * SGN>(tp, h0, w, acc);
  seg_one<  9,  14,  2 * SGN>(tp, h0, w, acc);
  seg_one< 15,  19,  3 * SGN>(tp, h0, w, acc);
  seg_one< 20,  24,  4 * SGN>(tp, h0, w, acc);
}

// analytic 1/N for the slant filters (A=0 => -10deg, A=2 => +10deg)
template<int A>
__device__ __forceinline__ float rcpcnt(int h, int w) {
  if (h >= 24 && h <= 2023 && w >= 4 && w <= 2043) return 1.0f / 49.0f;
  int cnt = 0;
  const int sgn = (A == 0) ? -1 : 1;
#pragma unroll
  for (int j = 0; j < 9; ++j) {
    const int ww = w + sgn * CO[j];
    const int ov = min(h + CE[j], HH - 1) - max(h + CS[j], 0) + 1;
    if (ww >= 0 && ww < WW && ov > 0) cnt += ov;
  }
  return 1.0f / (float)cnt;
}

// 1/N for the vertical filter: depends on h only
__device__ __forceinline__ float rcpcnt1(int h) {
  return 1.0f / (float)(min(h + 24, HH - 1) - max(h - 24, 0) + 1);
}

// ---- slant pass A: bp = filt(tcur)/N ----
template<int A>
__global__ __launch_bounds__(256) void passA(const __half* __restrict__ tcur,
                                             __half* __restrict__ bp) {
  const int w  = blockIdx.x * 256 + threadIdx.x;
  const int h0 = blockIdx.y * ROWS;
  float acc[ROWS];
  filt_slant<(A == 0) ? -1 : 1>(tcur, h0, w, acc);
#pragma unroll
  for (int r = 0; r < ROWS; ++r) {
    const int h = h0 + r;
    bp[(h + PADT) * SW + (w + PADL)] = __float2half(acc[r] * rcpcnt<A>(h, w));
  }
}

// ---- slant pass B (mid): tcur -= filt(bp)/N (in place) ----
template<int A>
__global__ __launch_bounds__(256) void passB(const __half* __restrict__ bp,
                                             __half* __restrict__ tcur) {
  const int w  = blockIdx.x * 256 + threadIdx.x;
  const int h0 = blockIdx.y * ROWS;
  float acc[ROWS];
  filt_slant<(A == 0) ? -1 : 1>(bp, h0, w, acc);
#pragma unroll
  for (int r = 0; r < ROWS; ++r) {
    const int h = h0 + r;
    const size_t ip = (size_t)(h + PADT) * SW + (w + PADL);
    tcur[ip] = __float2half(__half2float(tcur[ip]) - acc[r] * rcpcnt<A>(h, w));
  }
}

// ---- vertical (0 deg) passes, 2 cols/thread via aligned __half2 loads ----
__global__ __launch_bounds__(256) void passA1v(const __half* __restrict__ tcur,
                                               __half* __restrict__ bp) {
  const int w2 = (blockIdx.x * 256 + threadIdx.x) * 2;
  const int h0 = blockIdx.y * ROWS;
  const size_t st = SW / 2;
  const __half2* p = (const __half2*)(tcur + (size_t)(h0 - 24 + PADT) * SW) + (w2 + PADL) / 2;
  float sx = 0.0f, sy = 0.0f;
#pragma unroll
  for (int k = 0; k < 48; ++k) {
    const float2 v = __half22float2(p[k * st]); sx += v.x; sy += v.y;
  }
#pragma unroll
  for (int r = 0; r < ROWS; ++r) {
    const int h = h0 + r;
    const float2 vin = __half22float2(p[(48 + r) * st]);
    const float rc = rcpcnt1(h);
    __half2* o = (__half2*)(bp + (size_t)(h + PADT) * SW + (w2 + PADL));
    *o = __floats2half2_rn((sx + vin.x) * rc, (sy + vin.y) * rc);
    const float2 vout = __half22float2(p[r * st]);
    sx += vin.x - vout.x; sy += vin.y - vout.y;
  }
}

__global__ __launch_bounds__(256) void passB1v(const __half* __restrict__ bp,
                                               __half* __restrict__ tcur) {
  const int w2 = (blockIdx.x * 256 + threadIdx.x) * 2;
  const int h0 = blockIdx.y * ROWS;
  const size_t st = SW / 2;
  const __half2* p = (const __half2*)(bp + (size_t)(h0 - 24 + PADT) * SW) + (w2 + PADL) / 2;
  float sx = 0.0f, sy = 0.0f;
#pragma unroll
  for (int k = 0; k < 48; ++k) {
    const float2 v = __half22float2(p[k * st]); sx += v.x; sy += v.y;
  }
#pragma unroll
  for (int r = 0; r < ROWS; ++r) {
    const int h = h0 + r;
    const float2 vin = __half22float2(p[(48 + r) * st]);
    const float rc = rcpcnt1(h);
    __half2* o = (__half2*)(tcur + (size_t)(h + PADT) * SW + (w2 + PADL));
    const float2 cur = __half22float2(*o);
    *o = __floats2half2_rn(cur.x - (sx + vin.x) * rc, cur.y - (sy + vin.y) * rc);
    const float2 vout = __half22float2(p[r * st]);
    sx += vin.x - vout.x; sy += vin.y - vout.y;
  }
}

// ---- final slant pass B: res = t0 - (tcur - filt(bp)/N); tcur <- res;
// block-reduced global |res| max -> atomicMax (1 atomic per block) ----
template<int A>
__global__ __launch_bounds__(256) void passBF(const __half* __restrict__ bp,
                                              __half* __restrict__ tcur,
                                              const __half* __restrict__ t0h,
                                              unsigned int* __restrict__ scaleU) {
  const int w  = blockIdx.x * 256 + threadIdx.x;
  const int h0 = blockIdx.y * ROWS;
  float acc[ROWS];
  filt_slant<(A == 0) ? -1 : 1>(bp, h0, w, acc);
  float m = 0.0f;
#pragma unroll
  for (int r = 0; r < ROWS; ++r) {
    const int h = h0 + r;
    const size_t i  = (size_t)h * WW + w;
    const size_t ip = (size_t)(h + PADT) * SW + (w + PADL);
    const float res = __half2float(t0h[i]) - __half2float(tcur[ip]) +
                      acc[r] * rcpcnt<A>(h, w);
    tcur[ip] = __float2half(res);
    m = fmaxf(m, fabsf(res));
  }
#pragma unroll
  for (int off = 32; off >= 1; off >>= 1) m = fmaxf(m, __shfl_xor(m, off));
  __shared__ float red[4];
  if ((threadIdx.x & 63) == 0) red[threadIdx.x >> 6] = m;
  __syncthreads();
  if (threadIdx.x == 0) {
    const float bm = fmaxf(fmaxf(red[0], red[1]), fmaxf(red[2], red[3]));
    atomicMax(scaleU, __float_as_uint(bm));
  }
}

// ---- quantize D (in tcur, padded fp16) into col-pair-dup int8:
// P2[h*WW+x] = bytes (q[h][x], q[h][x+1]); 4 cols/thread ----
__global__ __launch_bounds__(256) void quantP2(const __half* __restrict__ tcur,
                                               const unsigned int* __restrict__ scaleU,
                                               unsigned int* __restrict__ P2u) {
  const int i = blockIdx.x * 256 + threadIdx.x;   // over HH * (WW/4)
  const int row = i >> 9, c4 = (i & 511) * 4;
  const float mg = __uint_as_float(*scaleU);
  const float inv = (mg > 0.0f) ? 127.0f / mg : 0.0f;
  const __half* base = tcur + (size_t)(row + PADT) * SW + (c4 + PADL);
  const float2 v01 = __half22float2(*(const __half2*)(base));
  const float2 v23 = __half22float2(*(const __half2*)(base + 2));
  const float2 v45 = __half22float2(*(const __half2*)(base + 4)); // c4+4 may be pad zero (weight-0 use only)
  int q0 = min(max((int)rintf(v01.x * inv), -127), 127);
  int q1 = min(max((int)rintf(v01.y * inv), -127), 127);
  int q2 = min(max((int)rintf(v23.x * inv), -127), 127);
  int q3 = min(max((int)rintf(v23.y * inv), -127), 127);
  int q4 = min(max((int)rintf(v45.x * inv), -127), 127);
  uint2 o;
  o.x = (unsigned int)(q0 & 0xff) | ((unsigned int)(q1 & 0xff) << 8) |
        ((unsigned int)(q1 & 0xff) << 16) | ((unsigned int)(q2 & 0xff) << 24);
  o.y = (unsigned int)(q2 & 0xff) | ((unsigned int)(q3 & 0xff) << 8) |
        ((unsigned int)(q3 & 0xff) << 16) | ((unsigned int)(q4 & 0xff) << 24);
  *(uint2*)(P2u + ((size_t)row * WW + c4) / 2) = o;
}

// zero the pad frame of both fp16 staging buffers (+ init scaleU)
__global__ __launch_bounds__(64) void zeropad(__half* __restrict__ tp, __half* __restrict__ bp,
                                              unsigned int* __restrict__ scaleU) {
  if (blockIdx.x == 0 && blockIdx.y == 0 && threadIdx.x == 0) *scaleU = 0u;
  __half* buf = blockIdx.y ? bp : tp;
  const int row = blockIdx.x;
  __half* r = buf + (size_t)row * SW;
  const __half z = __float2half(0.0f);
  if (row < PADT || row >= PADT + HH) {
    for (int c = threadIdx.x; c < SW; c += 64) r[c] = z;
  } else if (threadIdx.x < PADL) {
    r[threadIdx.x] = z;
    r[PADL + WW + threadIdx.x] = z;
  }
}

// tcur interior = t0h = y - X
__global__ __launch_bounds__(256) void sub2pad(const float* __restrict__ y,
                                               const float* __restrict__ X,
                                               __half* __restrict__ tcur,
                                               __half* __restrict__ t0h) {
  const int i = blockIdx.x * 256 + threadIdx.x;
  const int h = i >> 11, w = i & (WW - 1);
  const __half d = __float2half(y[i] - X[i]);
  tcur[(h + PADT) * SW + (w + PADL)] = d;
  t0h[i] = d;
}

__device__ __forceinline__ float reflectf(float x, int size) {
  const float span = (float)(size - 1);
  const float ax = fabsf(x);
  const float extra = fmodf(ax, span);
  const float flips = floorf(ax / span);
  float r = (fmodf(flips, 2.0f) == 0.0f) ? extra : (span - extra);
  return fminf(fmaxf(r, 0.0f), span);
}

__global__ __launch_bounds__(256) void gather_k(const unsigned short* __restrict__ P2,
                                                const unsigned int* __restrict__ scaleU,
                                                const unsigned long long* __restrict__ coorU,
                                                const float* __restrict__ hX,
                                                float* __restrict__ out) {
  const int i = blockIdx.x * 256 + threadIdx.x;
  const unsigned long long cu = __builtin_nontemporal_load(&coorU[i]);
  union { unsigned long long u; float f[2]; } cc; cc.u = cu;
  const float gx = reflectf((cc.f[0] + 1.0f) * 0.5f * (float)(WW - 1), WW);
  const float gy = reflectf((cc.f[1] + 1.0f) * 0.5f * (float)(HH - 1), HH);
  const float x0 = floorf(gx), y0 = floorf(gy);
  const float wx = gx - x0, wy = gy - y0;
  const int xi0 = min(max((int)x0, 0), WW - 1);
  const int yi0 = min(max((int)y0, 0), HH - 1);
  const int yi1 = min(max((int)(y0 + 1.0f), 0), HH - 1);
  const unsigned short u0 = P2[(size_t)yi0 * WW + xi0];   // (v00, v01)
  const unsigned short u1 = P2[(size_t)yi1 * WW + xi0];   // (v10, v11)
  const float v00 = (float)(signed char)(u0 & 0xff);
  const float v01 = (float)(signed char)(u0 >> 8);
  const float v10 = (float)(signed char)(u1 & 0xff);
  const float v11 = (float)(signed char)(u1 >> 8);
  const float sc = __uint_as_float(*scaleU) * (1.0f / 127.0f);  // wave-uniform
  const float hx = __builtin_nontemporal_load(&hX[i]);
  const float bil = v00 * (1.0f - wx) * (1.0f - wy) + v01 * wx * (1.0f - wy) +
                    v10 * (1.0f - wx) * wy + v11 * wx * wy;
  __builtin_nontemporal_store(bil * sc + hx, &out[i]);
}

extern "C" void kernel_launch(void* const* d_in, const int* in_sizes, int n_in,
                              void* d_out, int out_size, void* d_ws, size_t ws_size,
                              hipStream_t stream) {
  const float* X    = (const float*)d_in[0];
  const float* y    = (const float*)d_in[1];
  const float* hX   = (const float*)d_in[2];
  const float* coor = (const float*)d_in[3];
  float* out = (float*)d_out;

  __half* tcur = (__half*)d_ws;                      // padded t, fp16,  8.65 MB
  __half* bp   = tcur + PadElems;                    // padded b, fp16,  8.65 MB
  __half* t0h  = bp + PadElems;                      // t0 = y-X, fp16,  8.39 MB
  unsigned int* P2u = (unsigned int*)(t0h + (size_t)HH * WW);  // col-pair int8 D, 8.39 MB... actually 4.19 MB used
  unsigned int* scaleU = P2u + (size_t)HH * WW / 2;  // 4 B

  const int n = HH * WW;
  dim3 fgrd(WW / 256, HH / ROWS, 1);
  dim3 vgrd(WW / 512, HH / ROWS, 1);

  zeropad<<<dim3(PROWS, 2, 1), 64, 0, stream>>>(tcur, bp, scaleU);
  sub2pad<<<n / 256, 256, 0, stream>>>(y, X, tcur, t0h);

  // iteration 0: -10deg
  passA<0><<<fgrd, 256, 0, stream>>>(tcur, bp);
  passB<0><<<fgrd, 256, 0, stream>>>(bp, tcur);
  // iteration 1: 0deg (vertical, half2 2-col path)
  passA1v<<<vgrd, 256, 0, stream>>>(tcur, bp);
  passB1v<<<vgrd, 256, 0, stream>>>(bp, tcur);
  // iteration 2: +10deg  (tcur <- D = t0 - t3; global max into scaleU)
  passA<2><<<fgrd, 256, 0, stream>>>(tcur, bp);
  passBF<2><<<fgrd, 256, 0, stream>>>(bp, tcur, t0h, scaleU);

  quantP2<<<(n / 4) / 256, 256, 0, stream>>>(tcur, scaleU, P2u);
  gather_k<<<n / 256, 256, 0, stream>>>((const unsigned short*)P2u, scaleU,
                                        (const unsigned long long*)coor, hX, out);
}

// Round 9
// 174.750 us; speedup vs baseline: 1.3464x; 1.2421x over previous
//
#include <hip/hip_runtime.h>
#include <hip/hip_fp16.h>

static constexpr int HH = 2048;
static constexpr int WW = 2048;
static constexpr int PADT = 24;   // top/bottom pad rows
static constexpr int PADL = 8;    // left/right pad cols
static constexpr int SW   = WW + 2 * PADL;          // 2064
static constexpr int PROWS = HH + 2 * PADT;         // 2096
static constexpr size_t PadElems = (size_t)PROWS * SW;
static constexpr int ROWS = 16;   // output rows per thread in filter kernels

// segment tables for +10 deg: lval(d)=round(d*tan(10deg)), runs of constant offset
__device__ constexpr int CS[9] = {-24,-19,-14,-8,-2, 3, 9,15,20};
__device__ constexpr int CE[9] = {-20,-15, -9,-3, 2, 8,14,19,24};
__device__ constexpr int CO[9] = { -4, -3, -2,-1, 0, 1, 2, 3, 4};

// ---- one slanted segment: vertical run [SS,EE] at col offset OO ----
template<int SS, int EE, int OO>
__device__ __forceinline__ void seg_one(const __half* __restrict__ tp, int h0, int w,
                                        float* __restrict__ acc) {
  constexpr int L = EE - SS + 1;        // 5 or 6
  const __half* p = tp + (h0 + SS + PADT) * SW + (w + OO + PADL);
  float ring[L - 1];
  float s = 0.0f;
#pragma unroll
  for (int k = 0; k < L - 1; ++k) { float v = __half2float(p[k * SW]); ring[k] = v; s += v; }
#pragma unroll
  for (int r = 0; r < ROWS; ++r) {
    float v = __half2float(p[(L - 1 + r) * SW]);
    acc[r] += s + v;
    s += v - ring[r % (L - 1)];
    ring[r % (L - 1)] = v;
  }
}

template<int SGN>   // +1 => +10deg, -1 => -10deg
__device__ __forceinline__ void filt_slant(const __half* __restrict__ tp, int h0, int w,
                                           float* __restrict__ acc) {
#pragma unroll
  for (int r = 0; r < ROWS; ++r) acc[r] = 0.0f;
  seg_one<-24, -20, -4 * SGN>(tp, h0, w, acc);
  seg_one<-19, -15, -3 * SGN>(tp, h0, w, acc);
  seg_one<-14,  -9, -2 * SGN>(tp, h0, w, acc);
  seg_one< -8,  -3, -1 * SGN>(tp, h0, w, acc);
  seg_one< -2,   2,  0      >(tp, h0, w, acc);
  seg_one<  3,   8,  1 * SGN>(tp, h0, w, acc);
  seg_one<  9,  14,  2 * SGN>(tp, h0, w, acc);
  seg_one< 15,  19,  3 * SGN>(tp, h0, w, acc);
  seg_one< 20,  24,  4 * SGN>(tp, h0, w, acc);
}

// analytic 1/N for the slant filters (A=0 => -10deg, A=2 => +10deg)
template<int A>
__device__ __forceinline__ float rcpcnt(int h, int w) {
  if (h >= 24 && h <= 2023 && w >= 4 && w <= 2043) return 1.0f / 49.0f;
  int cnt = 0;
  const int sgn = (A == 0) ? -1 : 1;
#pragma unroll
  for (int j = 0; j < 9; ++j) {
    const int ww = w + sgn * CO[j];
    const int ov = min(h + CE[j], HH - 1) - max(h + CS[j], 0) + 1;
    if (ww >= 0 && ww < WW && ov > 0) cnt += ov;
  }
  return 1.0f / (float)cnt;
}

// 1/N for the vertical filter: depends on h only
__device__ __forceinline__ float rcpcnt1(int h) {
  return 1.0f / (float)(min(h + 24, HH - 1) - max(h - 24, 0) + 1);
}

// ---- slant pass A: bp = filt(tcur)/N ----
template<int A>
__global__ __launch_bounds__(256) void passA(const __half* __restrict__ tcur,
                                             __half* __restrict__ bp) {
  const int w  = blockIdx.x * 256 + threadIdx.x;
  const int h0 = blockIdx.y * ROWS;
  float acc[ROWS];
  filt_slant<(A == 0) ? -1 : 1>(tcur, h0, w, acc);
#pragma unroll
  for (int r = 0; r < ROWS; ++r) {
    const int h = h0 + r;
    bp[(h + PADT) * SW + (w + PADL)] = __float2half(acc[r] * rcpcnt<A>(h, w));
  }
}

// ---- slant pass B (mid): tcur -= filt(bp)/N (in place) ----
template<int A>
__global__ __launch_bounds__(256) void passB(const __half* __restrict__ bp,
                                             __half* __restrict__ tcur) {
  const int w  = blockIdx.x * 256 + threadIdx.x;
  const int h0 = blockIdx.y * ROWS;
  float acc[ROWS];
  filt_slant<(A == 0) ? -1 : 1>(bp, h0, w, acc);
#pragma unroll
  for (int r = 0; r < ROWS; ++r) {
    const int h = h0 + r;
    const size_t ip = (size_t)(h + PADT) * SW + (w + PADL);
    tcur[ip] = __float2half(__half2float(tcur[ip]) - acc[r] * rcpcnt<A>(h, w));
  }
}

// ---- vertical (0 deg) passes, 2 cols/thread via aligned __half2 loads ----
__global__ __launch_bounds__(256) void passA1v(const __half* __restrict__ tcur,
                                               __half* __restrict__ bp) {
  const int w2 = (blockIdx.x * 256 + threadIdx.x) * 2;
  const int h0 = blockIdx.y * ROWS;
  const size_t st = SW / 2;
  const __half2* p = (const __half2*)(tcur + (size_t)(h0 - 24 + PADT) * SW) + (w2 + PADL) / 2;
  float sx = 0.0f, sy = 0.0f;
#pragma unroll
  for (int k = 0; k < 48; ++k) {
    const float2 v = __half22float2(p[k * st]); sx += v.x; sy += v.y;
  }
#pragma unroll
  for (int r = 0; r < ROWS; ++r) {
    const int h = h0 + r;
    const float2 vin = __half22float2(p[(48 + r) * st]);
    const float rc = rcpcnt1(h);
    __half2* o = (__half2*)(bp + (size_t)(h + PADT) * SW + (w2 + PADL));
    *o = __floats2half2_rn((sx + vin.x) * rc, (sy + vin.y) * rc);
    const float2 vout = __half22float2(p[r * st]);
    sx += vin.x - vout.x; sy += vin.y - vout.y;
  }
}

__global__ __launch_bounds__(256) void passB1v(const __half* __restrict__ bp,
                                               __half* __restrict__ tcur) {
  const int w2 = (blockIdx.x * 256 + threadIdx.x) * 2;
  const int h0 = blockIdx.y * ROWS;
  const size_t st = SW / 2;
  const __half2* p = (const __half2*)(bp + (size_t)(h0 - 24 + PADT) * SW) + (w2 + PADL) / 2;
  float sx = 0.0f, sy = 0.0f;
#pragma unroll
  for (int k = 0; k < 48; ++k) {
    const float2 v = __half22float2(p[k * st]); sx += v.x; sy += v.y;
  }
#pragma unroll
  for (int r = 0; r < ROWS; ++r) {
    const int h = h0 + r;
    const float2 vin = __half22float2(p[(48 + r) * st]);
    const float rc = rcpcnt1(h);
    __half2* o = (__half2*)(tcur + (size_t)(h + PADT) * SW + (w2 + PADL));
    const float2 cur = __half22float2(*o);
    *o = __floats2half2_rn(cur.x - (sx + vin.x) * rc, cur.y - (sy + vin.y) * rc);
    const float2 vout = __half22float2(p[r * st]);
    sx += vin.x - vout.x; sy += vin.y - vout.y;
  }
}

// ---- final slant pass B: res = t0 - (tcur - filt(bp)/N); tcur <- res;
// block-reduced global |res| max -> atomicMax (1 atomic per block) ----
template<int A>
__global__ __launch_bounds__(256) void passBF(const __half* __restrict__ bp,
                                              __half* __restrict__ tcur,
                                              const __half* __restrict__ t0h,
                                              unsigned int* __restrict__ scaleU) {
  const int w  = blockIdx.x * 256 + threadIdx.x;
  const int h0 = blockIdx.y * ROWS;
  float acc[ROWS];
  filt_slant<(A == 0) ? -1 : 1>(bp, h0, w, acc);
  float m = 0.0f;
#pragma unroll
  for (int r = 0; r < ROWS; ++r) {
    const int h = h0 + r;
    const size_t i  = (size_t)h * WW + w;
    const size_t ip = (size_t)(h + PADT) * SW + (w + PADL);
    const float res = __half2float(t0h[i]) - __half2float(tcur[ip]) +
                      acc[r] * rcpcnt<A>(h, w);
    tcur[ip] = __float2half(res);
    m = fmaxf(m, fabsf(res));
  }
#pragma unroll
  for (int off = 32; off >= 1; off >>= 1) m = fmaxf(m, __shfl_xor(m, off));
  __shared__ float red[4];
  if ((threadIdx.x & 63) == 0) red[threadIdx.x >> 6] = m;
  __syncthreads();
  if (threadIdx.x == 0) {
    const float bm = fmaxf(fmaxf(red[0], red[1]), fmaxf(red[2], red[3]));
    atomicMax(scaleU, __float_as_uint(bm));
  }
}

// ---- quantize D (in tcur, padded fp16) into 8-row-packed int8 cells:
// V8[s*WW + x] byte j = q[8s+j][x]  (footprint 4.19 MB, no duplication) ----
__global__ __launch_bounds__(256) void quantV8(const __half* __restrict__ tcur,
                                               const unsigned int* __restrict__ scaleU,
                                               unsigned long long* __restrict__ V8) {
  const int i = blockIdx.x * 256 + threadIdx.x;   // over (HH/8) * WW cells
  const int s = i >> 11, x = i & (WW - 1);
  const float mg = __uint_as_float(*scaleU);
  const float inv = (mg > 0.0f) ? 127.0f / mg : 0.0f;
  const __half* base = tcur + (size_t)(8 * s + PADT) * SW + (x + PADL);
  unsigned long long v = 0;
#pragma unroll
  for (int j = 0; j < 8; ++j) {
    const float f = __half2float(base[(size_t)j * SW]);
    const int q = min(max((int)rintf(f * inv), -127), 127);
    v |= (unsigned long long)(unsigned char)(q & 0xff) << (8 * j);
  }
  V8[i] = v;
}

// zero the pad frame of both fp16 staging buffers (+ init scaleU)
__global__ __launch_bounds__(64) void zeropad(__half* __restrict__ tp, __half* __restrict__ bp,
                                              unsigned int* __restrict__ scaleU) {
  if (blockIdx.x == 0 && blockIdx.y == 0 && threadIdx.x == 0) *scaleU = 0u;
  __half* buf = blockIdx.y ? bp : tp;
  const int row = blockIdx.x;
  __half* r = buf + (size_t)row * SW;
  const __half z = __float2half(0.0f);
  if (row < PADT || row >= PADT + HH) {
    for (int c = threadIdx.x; c < SW; c += 64) r[c] = z;
  } else if (threadIdx.x < PADL) {
    r[threadIdx.x] = z;
    r[PADL + WW + threadIdx.x] = z;
  }
}

// tcur interior = t0h = y - X
__global__ __launch_bounds__(256) void sub2pad(const float* __restrict__ y,
                                               const float* __restrict__ X,
                                               __half* __restrict__ tcur,
                                               __half* __restrict__ t0h) {
  const int i = blockIdx.x * 256 + threadIdx.x;
  const int h = i >> 11, w = i & (WW - 1);
  const __half d = __float2half(y[i] - X[i]);
  tcur[(h + PADT) * SW + (w + PADL)] = d;
  t0h[i] = d;
}

__device__ __forceinline__ float reflectf(float x, int size) {
  const float span = (float)(size - 1);
  const float ax = fabsf(x);
  const float extra = fmodf(ax, span);
  const float flips = floorf(ax / span);
  float r = (fmodf(flips, 2.0f) == 0.0f) ? extra : (span - extra);
  return fminf(fmaxf(r, 0.0f), span);
}

__global__ __launch_bounds__(256) void gather_k(const unsigned long long* __restrict__ V8,
                                                const unsigned int* __restrict__ scaleU,
                                                const unsigned long long* __restrict__ coorU,
                                                const float* __restrict__ hX,
                                                float* __restrict__ out) {
  const int i = blockIdx.x * 256 + threadIdx.x;
  const unsigned long long cu = __builtin_nontemporal_load(&coorU[i]);
  union { unsigned long long u; float f[2]; } cc; cc.u = cu;
  const float gx = reflectf((cc.f[0] + 1.0f) * 0.5f * (float)(WW - 1), WW);
  const float gy = reflectf((cc.f[1] + 1.0f) * 0.5f * (float)(HH - 1), HH);
  const float x0 = floorf(gx), y0 = floorf(gy);
  const float wx = gx - x0, wy = gy - y0;
  const int xi0 = min(max((int)x0, 0), WW - 1);
  const int xi1 = min(xi0 + 1, WW - 1);
  const int yi0 = min(max((int)y0, 0), HH - 1);
  const int yi1 = min(max((int)(y0 + 1.0f), 0), HH - 1);
  const int s0 = yi0 >> 3, s1 = yi1 >> 3;
  const int j0 = (yi0 & 7) * 8, j1 = (yi1 & 7) * 8;
  const unsigned long long c00 = V8[(size_t)s0 * WW + xi0];
  const unsigned long long c01 = V8[(size_t)s0 * WW + xi1];
  unsigned long long c10 = c00, c11 = c01;
  if (s1 != s0) {                         // ~1/8 of lanes: next 8-row group
    c10 = V8[(size_t)s1 * WW + xi0];
    c11 = V8[(size_t)s1 * WW + xi1];
  }
  const float v00 = (float)(signed char)(c00 >> j0);
  const float v01 = (float)(signed char)(c01 >> j0);
  const float v10 = (float)(signed char)(c10 >> j1);
  const float v11 = (float)(signed char)(c11 >> j1);
  const float sc = __uint_as_float(*scaleU) * (1.0f / 127.0f);  // wave-uniform
  const float hx = __builtin_nontemporal_load(&hX[i]);
  const float bil = v00 * (1.0f - wx) * (1.0f - wy) + v01 * wx * (1.0f - wy) +
                    v10 * (1.0f - wx) * wy + v11 * wx * wy;
  __builtin_nontemporal_store(bil * sc + hx, &out[i]);
}

extern "C" void kernel_launch(void* const* d_in, const int* in_sizes, int n_in,
                              void* d_out, int out_size, void* d_ws, size_t ws_size,
                              hipStream_t stream) {
  const float* X    = (const float*)d_in[0];
  const float* y    = (const float*)d_in[1];
  const float* hX   = (const float*)d_in[2];
  const float* coor = (const float*)d_in[3];
  float* out = (float*)d_out;

  __half* tcur = (__half*)d_ws;                      // padded t, fp16,  8.65 MB
  __half* bp   = tcur + PadElems;                    // padded b, fp16,  8.65 MB
  __half* t0h  = bp + PadElems;                      // t0 = y-X, fp16,  8.39 MB
  unsigned long long* V8 = (unsigned long long*)(t0h + (size_t)HH * WW);  // 4.19 MB
  unsigned int* scaleU = (unsigned int*)(V8 + (size_t)(HH / 8) * WW);     // 4 B

  const int n = HH * WW;
  dim3 fgrd(WW / 256, HH / ROWS, 1);
  dim3 vgrd(WW / 512, HH / ROWS, 1);

  zeropad<<<dim3(PROWS, 2, 1), 64, 0, stream>>>(tcur, bp, scaleU);
  sub2pad<<<n / 256, 256, 0, stream>>>(y, X, tcur, t0h);

  // iteration 0: -10deg
  passA<0><<<fgrd, 256, 0, stream>>>(tcur, bp);
  passB<0><<<fgrd, 256, 0, stream>>>(bp, tcur);
  // iteration 1: 0deg (vertical, half2 2-col path)
  passA1v<<<vgrd, 256, 0, stream>>>(tcur, bp);
  passB1v<<<vgrd, 256, 0, stream>>>(bp, tcur);
  // iteration 2: +10deg  (tcur <- D = t0 - t3; global max into scaleU)
  passA<2><<<fgrd, 256, 0, stream>>>(tcur, bp);
  passBF<2><<<fgrd, 256, 0, stream>>>(bp, tcur, t0h, scaleU);

  quantV8<<<(n / 8) / 256, 256, 0, stream>>>(tcur, scaleU, V8);
  gather_k<<<n / 256, 256, 0, stream>>>(V8, scaleU, (const unsigned long long*)coor, hX, out);
}